// Round 1
// baseline (412.700 us; speedup 1.0000x reference)
//
#include <hip/hip_runtime.h>

// CRF-RNN mean-field, dense Gaussian kernels computed on the fly.
// N = 24*24*16 = 9216, C = 2, 5 iterations.
//
// Key identity: -0.5*||fi-fj||^2 = fi.fj - 0.5||fi||^2 - 0.5||fj||^2
// Spatial feats  fs = pos/3   -> ds = fs_i . fs_j
// Bilateral feats = [pos/160, I/3]; its spatial dot = (9/25600)*ds, so both
// exponents share one 3-term dot product. exp(x) computed as exp2(L*x).

#define NPTS 9216
#define JS 24          // j-split (chunks)
#define CHUNK 384      // NPTS / JS
#define NBLK 36        // NPTS / 256

static __device__ __forceinline__ float myexp2(float x) { return exp2f(x); }

#define LOG2E 1.4426950408889634f
#define C2L   (LOG2E * (9.0f / 25600.0f))

__global__ __launch_bounds__(256)
void precompute_kernel(const float* __restrict__ u,
                       const float* __restrict__ rgb,
                       float4* __restrict__ featA,
                       float2* __restrict__ featB,
                       float2* __restrict__ qbuf) {
    int i = blockIdx.x * 256 + threadIdx.x;
    if (i >= NPTS) return;
    int z = i / 384;
    int r = i - z * 384;
    int y = r / 16;
    int x = r - y * 16;
    float fz = (float)z, fy = (float)y, fx = (float)x;
    // spatial features pos/3
    float fsz = fz * (1.0f / 3.0f), fsy = fy * (1.0f / 3.0f), fsx = fx * (1.0f / 3.0f);
    float as_ = -0.5f * (fsx * fsx + fsy * fsy + fsz * fsz);
    float I = rgb[i];
    float Ii3 = I * (1.0f / 3.0f);
    // bilateral: |pos/160|^2 + (I/3)^2
    float bsq = (fx * fx + fy * fy + fz * fz) * (1.0f / 25600.0f);
    float ab = -0.5f * (bsq + Ii3 * Ii3);
    featA[i] = make_float4(fsz, fsy, fsx, as_ * LOG2E);
    featB[i] = make_float2(Ii3, ab * LOG2E);
    qbuf[i] = make_float2(u[2 * i], u[2 * i + 1]);
}

__global__ __launch_bounds__(256)
void accum_kernel(const float4* __restrict__ featA,
                  const float2* __restrict__ featB,
                  const float2* __restrict__ qbuf,
                  float* __restrict__ partial) {
    __shared__ float4 ldsA[CHUNK];   // fsz, fsy, fsx, asL_j
    __shared__ float4 ldsB[CHUNK];   // Ij3, abL_j, q0, q1
    const int tid = threadIdx.x;
    const int i = blockIdx.x * 256 + tid;
    const int j0 = blockIdx.y * CHUNK;

    for (int t = tid; t < CHUNK; t += 256) {
        int j = j0 + t;
        ldsA[t] = featA[j];
        float2 fb = featB[j];
        float2 qj = qbuf[j];
        ldsB[t] = make_float4(fb.x, fb.y, qj.x, qj.y);
    }

    float4 fa = featA[i];
    float2 fbI = featB[i];
    const float asL_i = fa.w;
    const float abL_i = fbI.y;
    const float Ii3L = fbI.x * LOG2E;
    __syncthreads();

    float sN = 0.f, s0 = 0.f, s1 = 0.f, bN = 0.f, b0 = 0.f, b1 = 0.f;
#pragma unroll 4
    for (int jj = 0; jj < CHUNK; ++jj) {
        float4 A = ldsA[jj];
        float4 B = ldsB[jj];
        float ds = fmaf(fa.x, A.x, fmaf(fa.y, A.y, fa.z * A.z));
        float ts = fmaf(LOG2E, ds, asL_i + A.w);
        float tb = fmaf(C2L, ds, fmaf(Ii3L, B.x, abL_i + B.y));
        float es = myexp2(ts);
        float eb = myexp2(tb);
        sN += es;
        bN += eb;
        s0 = fmaf(es, B.z, s0);
        s1 = fmaf(es, B.w, s1);
        b0 = fmaf(eb, B.z, b0);
        b1 = fmaf(eb, B.w, b1);
    }

    // layout: partial[(chunk*6 + k) * NPTS + i]  (coalesced writes & reads)
    float* dst = partial + (size_t)(blockIdx.y * 6) * NPTS + i;
    dst[0 * NPTS] = sN;
    dst[1 * NPTS] = s0;
    dst[2 * NPTS] = s1;
    dst[3 * NPTS] = bN;
    dst[4 * NPTS] = b0;
    dst[5 * NPTS] = b1;
}

__global__ __launch_bounds__(256)
void finalize_kernel(const float* __restrict__ partial,
                     const float* __restrict__ u,
                     const float* __restrict__ sw,
                     const float* __restrict__ bw,
                     const float* __restrict__ compat,
                     float2* __restrict__ qbuf,
                     float* __restrict__ out) {
    int i = blockIdx.x * 256 + threadIdx.x;
    if (i >= NPTS) return;
    float acc[6] = {0.f, 0.f, 0.f, 0.f, 0.f, 0.f};
    for (int ch = 0; ch < JS; ++ch) {
        const float* p = partial + (size_t)(ch * 6) * NPTS + i;
#pragma unroll
        for (int k = 0; k < 6; ++k) acc[k] += p[k * NPTS];
    }
    float s0 = acc[1] / acc[0];
    float s1 = acc[2] / acc[0];
    float b0 = acc[4] / acc[3];
    float b1 = acc[5] / acc[3];
    float m0 = s0 * sw[0] + b0 * bw[0];
    float m1 = s1 * sw[1] + b1 * bw[1];
    // pairwise = message @ compat^T : pair[c] = sum_k msg[k] * compat[c*2+k]
    float p0 = fmaf(compat[0], m0, compat[1] * m1);
    float p1 = fmaf(compat[2], m0, compat[3] * m1);
    float q0 = u[2 * i] - p0;
    float q1 = u[2 * i + 1] - p1;
    qbuf[i] = make_float2(q0, q1);
    if (out != nullptr) {
        out[2 * i] = q0;
        out[2 * i + 1] = q1;
    }
}

extern "C" void kernel_launch(void* const* d_in, const int* in_sizes, int n_in,
                              void* d_out, int out_size, void* d_ws, size_t ws_size,
                              hipStream_t stream) {
    const float* u      = (const float*)d_in[0];  // 9216*2
    const float* rgb    = (const float*)d_in[1];  // 9216
    const float* sw     = (const float*)d_in[2];  // 2
    const float* bw     = (const float*)d_in[3];  // 2
    const float* compat = (const float*)d_in[4];  // 4
    float* out = (float*)d_out;

    float* ws = (float*)d_ws;
    float4* featA   = (float4*)ws;                    // 4*NPTS floats
    float2* featB   = (float2*)(ws + 4 * NPTS);       // 2*NPTS floats
    float2* qbuf    = (float2*)(ws + 6 * NPTS);       // 2*NPTS floats
    float*  partial = ws + 8 * NPTS;                  // JS*6*NPTS floats (~5.3 MB)

    precompute_kernel<<<NBLK, 256, 0, stream>>>(u, rgb, featA, featB, qbuf);

    for (int it = 0; it < 5; ++it) {
        accum_kernel<<<dim3(NBLK, JS), 256, 0, stream>>>(featA, featB, qbuf, partial);
        finalize_kernel<<<NBLK, 256, 0, stream>>>(partial, u, sw, bw, compat, qbuf,
                                                  (it == 4) ? out : nullptr);
    }
}

// Round 2
// 118.104 us; speedup vs baseline: 3.4944x; 3.4944x over previous
//
#include <hip/hip_runtime.h>

// CRF-RNN mean-field via SEPARABLE Gaussian filtering.
// Grid 24(z) x 24(y) x 16(x), N=9216, C=2, 5 iterations.
//
// Ks (theta=3) = Gz (x) Gy (x) Gx  -- exact, full-width 1-D convs.
// Kb = S160_ij * E_i E_j * exp(I3_i*I3_j),  I3=I/3, E=exp(-I3^2/2),
//   exp(I3_i*I3_j) = sum_t (I3_i^t I3_j^t)/t!   (T=5 terms, err ~1e-7 rel)
// => (Kb q)_i = sum_t P_t[i]/t! * (S160 @ (P_t .* q))_i,  P_t = I3^t*E.
// norm_s is analytically separable; norm_b via same expansion on ones.

#define DD 24
#define HH 24
#define WW 16
#define SLICE 384            // HH*WW
#define NPTS 9216            // DD*SLICE
#define NT 5                 // Taylor terms
#define NF_ITER 12           // 2 spatial + 2*NT bilateral
#define LOG2E 1.4426950408889634f
#define K3L   (LOG2E / 18.0f)      // exponent coeff for theta=3:  exp(-d^2/18)
#define K160L (LOG2E / 51200.0f)   // theta=160: exp(-d^2/51200)

static __device__ __forceinline__ int iabs(int a) { return a < 0 ? -a : a; }

// ---------------- XY pass: one block per (z-slice, field) -------------------
// mode 0 (norm): field f in [0,NT): value = P_f
// mode 1 (iter): f in {0,1}: q_f (theta=3); f in [2,12): P_t * q_c, theta=160
__global__ __launch_bounds__(SLICE)
void xy_kernel(const float2* __restrict__ qsrc,
               const float* __restrict__ rgb,
               float* __restrict__ tmp, int mode) {
    __shared__ float g[DD];
    __shared__ float a[SLICE];
    __shared__ float b[SLICE];
    const int z = blockIdx.x;
    const int f = blockIdx.y;
    const int t = threadIdx.x;

    const bool spatial = (mode == 1) && (f < 2);
    const float k2 = spatial ? K3L : K160L;
    if (t < DD) g[t] = exp2f(-(float)(t * t) * k2);

    const int i = z * SLICE + t;
    float v;
    if (mode == 0) {
        float I3 = rgb[i] * (1.0f / 3.0f);
        float E = exp2f(-0.5f * LOG2E * I3 * I3);
        float P = E;
        for (int s = 0; s < f; ++s) P *= I3;
        v = P;
    } else {
        float2 q = qsrc[i];
        if (f < 2) {
            v = (f == 0) ? q.x : q.y;
        } else {
            int tt = (f - 2) >> 1;
            int c  = (f - 2) & 1;
            float I3 = rgb[i] * (1.0f / 3.0f);
            float E = exp2f(-0.5f * LOG2E * I3 * I3);
            float P = E;
            for (int s = 0; s < tt; ++s) P *= I3;
            v = P * (c ? q.y : q.x);
        }
    }
    a[t] = v;
    __syncthreads();

    const int y = t >> 4, x = t & 15;
    float s = 0.f;
#pragma unroll
    for (int xp = 0; xp < WW; ++xp)
        s = fmaf(g[iabs(x - xp)], a[(y << 4) + xp], s);
    b[t] = s;
    __syncthreads();

    float s2 = 0.f;
#pragma unroll
    for (int yp = 0; yp < HH; ++yp)
        s2 = fmaf(g[iabs(y - yp)], b[(yp << 4) + x], s2);
    tmp[f * NPTS + i] = s2;
}

// ---------------- Z pass for norm_b ----------------------------------------
__global__ __launch_bounds__(256)
void z_norm_kernel(const float* __restrict__ tmp,
                   const float* __restrict__ rgb,
                   float* __restrict__ norm_b) {
    __shared__ float gz[DD];
    const int tid = threadIdx.x;
    const int i = blockIdx.x * 256 + tid;
    const int z = i / SLICE;
    const int yx = i - z * SLICE;
    if (tid < DD) gz[tid] = exp2f(-(float)(tid * tid) * K160L);
    __syncthreads();

    float acc[NT] = {0.f, 0.f, 0.f, 0.f, 0.f};
    for (int zp = 0; zp < DD; ++zp) {
        float w = gz[iabs(z - zp)];
        const float* base = tmp + zp * SLICE + yx;
#pragma unroll
        for (int t = 0; t < NT; ++t) acc[t] = fmaf(w, base[t * NPTS], acc[t]);
    }
    const float invf[NT] = {1.f, 1.f, 0.5f, 1.f / 6.f, 1.f / 24.f};
    float I3 = rgb[i] * (1.0f / 3.0f);
    float P = exp2f(-0.5f * LOG2E * I3 * I3);
    float nb = 0.f;
#pragma unroll
    for (int t = 0; t < NT; ++t) { nb = fmaf(P * invf[t], acc[t], nb); P *= I3; }
    norm_b[i] = nb;
}

// ---------------- Z pass + mean-field update -------------------------------
__global__ __launch_bounds__(256)
void z_iter_kernel(const float* __restrict__ tmp,
                   const float* __restrict__ rgb,
                   const float* __restrict__ norm_b,
                   const float2* __restrict__ u2,
                   const float* __restrict__ sw,
                   const float* __restrict__ bw,
                   const float* __restrict__ compat,
                   float2* __restrict__ qdst,
                   float2* __restrict__ out) {
    __shared__ float g3[DD];
    __shared__ float g160[DD];
    __shared__ float ssx[WW];
    __shared__ float ssy[HH];
    const int tid = threadIdx.x;
    const int i = blockIdx.x * 256 + tid;
    const int z = i / SLICE;
    const int yx = i - z * SLICE;
    const int y = yx >> 4, x = yx & 15;

    if (tid < DD) g3[tid] = exp2f(-(float)(tid * tid) * K3L);
    else if (tid >= 32 && tid < 32 + DD) {
        int d = tid - 32;
        g160[d] = exp2f(-(float)(d * d) * K160L);
    }
    __syncthreads();
    if (tid < WW) {
        float s = 0.f;
        for (int xp = 0; xp < WW; ++xp) s += g3[iabs(tid - xp)];
        ssx[tid] = s;
    } else if (tid >= 64 && tid < 64 + HH) {
        int yy = tid - 64;
        float s = 0.f;
        for (int yp = 0; yp < HH; ++yp) s += g3[iabs(yy - yp)];
        ssy[yy] = s;
    }
    __syncthreads();

    float acc[NF_ITER];
#pragma unroll
    for (int f = 0; f < NF_ITER; ++f) acc[f] = 0.f;
    for (int zp = 0; zp < DD; ++zp) {
        float w3 = g3[iabs(z - zp)];
        float wb = g160[iabs(z - zp)];
        const float* base = tmp + zp * SLICE + yx;
        acc[0] = fmaf(w3, base[0 * NPTS], acc[0]);
        acc[1] = fmaf(w3, base[1 * NPTS], acc[1]);
#pragma unroll
        for (int f = 2; f < NF_ITER; ++f) acc[f] = fmaf(wb, base[f * NPTS], acc[f]);
    }

    float inv_ns = 1.0f / (ssy[z] * ssy[y] * ssx[x]);   // ssz == ssy (both 24)
    float s0 = acc[0] * inv_ns;
    float s1 = acc[1] * inv_ns;

    const float invf[NT] = {1.f, 1.f, 0.5f, 1.f / 6.f, 1.f / 24.f};
    float I3 = rgb[i] * (1.0f / 3.0f);
    float P = exp2f(-0.5f * LOG2E * I3 * I3);
    float b0 = 0.f, b1 = 0.f;
#pragma unroll
    for (int t = 0; t < NT; ++t) {
        float w = P * invf[t];
        b0 = fmaf(w, acc[2 + 2 * t], b0);
        b1 = fmaf(w, acc[3 + 2 * t], b1);
        P *= I3;
    }
    float inv_nb = 1.0f / norm_b[i];
    b0 *= inv_nb;
    b1 *= inv_nb;

    float m0 = s0 * sw[0] + b0 * bw[0];
    float m1 = s1 * sw[1] + b1 * bw[1];
    float p0 = fmaf(compat[0], m0, compat[1] * m1);
    float p1 = fmaf(compat[2], m0, compat[3] * m1);
    float2 uu = u2[i];
    float2 qn = make_float2(uu.x - p0, uu.y - p1);
    qdst[i] = qn;
    if (out != nullptr) out[i] = qn;
}

extern "C" void kernel_launch(void* const* d_in, const int* in_sizes, int n_in,
                              void* d_out, int out_size, void* d_ws, size_t ws_size,
                              hipStream_t stream) {
    const float*  u      = (const float*)d_in[0];   // N*2
    const float*  rgb    = (const float*)d_in[1];   // N
    const float*  sw     = (const float*)d_in[2];
    const float*  bw     = (const float*)d_in[3];
    const float*  compat = (const float*)d_in[4];
    const float2* u2     = (const float2*)u;
    float2* out = (float2*)d_out;

    float* ws = (float*)d_ws;
    float*  tmp    = ws;                              // NF_ITER * N floats
    float*  norm_b = ws + NF_ITER * NPTS;             // N floats
    float2* qbuf   = (float2*)(ws + (NF_ITER + 1) * NPTS);  // 2N floats

    // norm_b precompute: filter P_t (t=0..NT-1) through S160
    xy_kernel<<<dim3(DD, NT), SLICE, 0, stream>>>(nullptr, rgb, tmp, 0);
    z_norm_kernel<<<NPTS / 256, 256, 0, stream>>>(tmp, rgb, norm_b);

    for (int it = 0; it < 5; ++it) {
        const float2* qsrc = (it == 0) ? u2 : (const float2*)qbuf;
        xy_kernel<<<dim3(DD, NF_ITER), SLICE, 0, stream>>>(qsrc, rgb, tmp, 1);
        z_iter_kernel<<<NPTS / 256, 256, 0, stream>>>(tmp, rgb, norm_b, u2,
                                                      sw, bw, compat, qbuf,
                                                      (it == 4) ? out : nullptr);
    }
}